// Round 3
// baseline (3492.999 us; speedup 1.0000x reference)
//
#include <hip/hip_runtime.h>

#define Bb 64
#define Tt 512
#define Dd 256
#define Hh 1024
#define G3 3072

// workspace layout
#define FLAG_BYTES 4096                        // 256 slots x 16 B
#define HH_OFF     FLAG_BYTES                  // [2][64][512] u32 (bf16-hi pairs) = 256 KB
#define HL_OFF     (FLAG_BYTES + 262144)       // [2][64][512] u32 (bf16-lo pairs)

typedef __attribute__((ext_vector_type(8))) __bf16 bf16x8;
typedef __attribute__((ext_vector_type(4))) float f32x4;

static __device__ __forceinline__ f32x4 mfma16(bf16x8 a, bf16x8 b, f32x4 c){
    return __builtin_amdgcn_mfma_f32_16x16x32_bf16(a, b, c, 0, 0, 0);
}

static __device__ __forceinline__ unsigned short bfbits(__bf16 v){
    return __builtin_bit_cast(unsigned short, v);
}

// gather embedding rows for timestep t into LDS x-buffer (hi/lo bf16 split),
// swizzled to match the MFMA A-fragment ds_read pattern. 128 threads (lt 0..127).
// Packed u64 LDS writes (8 per plane per thread) instead of 64 b16 writes.
__device__ __forceinline__ void gatherX(__bf16* sxh, __bf16* sxl,
                                        const int* inp, const float* emb,
                                        int m, int t, int lt)
{
    int row = lt >> 3, c8 = lt & 7;
    int grow = m*16 + row;
    int tok = inp[grow*Tt + t];
    const float* er = emb + (long)tok * Dd;
    int swz = (row & 7) << 4;
    #pragma unroll
    for (int qq = 0; qq < 8; ++qq){
        int c = c8 + qq*8;                       // 4-float chunk, 0..63
        float4 v = *(const float4*)(er + c*4);
        int boff = row*512 + ((c*8) ^ swz);      // byte offset, 8B-aligned
        float vv[4] = {v.x, v.y, v.z, v.w};
        unsigned long long Hp = 0, Lp = 0;
        #pragma unroll
        for (int e = 0; e < 4; ++e){
            __bf16 hb = (__bf16)vv[e];
            __bf16 lb = (__bf16)(vv[e] - (float)hb);
            Hp |= (unsigned long long)bfbits(hb) << (16*e);
            Lp |= (unsigned long long)bfbits(lb) << (16*e);
        }
        *(unsigned long long*)((char*)sxh + boff) = Hp;
        *(unsigned long long*)((char*)sxl + boff) = Lp;
    }
}

extern "C" __global__ void __launch_bounds__(512, 2)
gru_persist(const int* __restrict__ inp, const float* __restrict__ hid,
            const float* __restrict__ emb, const float* __restrict__ kern,
            const float* __restrict__ reck, const float* __restrict__ bias,
            float* __restrict__ out, unsigned char* __restrict__ ws)
{
    __shared__ __bf16 sHhi[16*1024];     // 32 KB, swizzled
    __shared__ __bf16 sHlo[16*1024];     // 32 KB
    __shared__ __bf16 sX[2][2][16*256];  // [buf][hi/lo], 32 KB total
    __shared__ float  sTile[8][272];     // [tile][kgrp*68 + r*16 + col]

    const int tid  = threadIdx.x;
    const int wid  = tid >> 6;
    const int lane = tid & 63;
    const int blk  = blockIdx.x;
    const int m = blk & 3;       // row group: rows 16m..16m+15
    const int n = blk >> 2;      // j group:  j = 16n..16n+15

    unsigned int* flags = (unsigned int*)ws;             // slot (m*64+n)*4, 16B stride
    unsigned int* hHpl = (unsigned int*)(ws + HH_OFF);   // [2][64][512] hi pairs
    unsigned int* hLpl = (unsigned int*)(ws + HL_OFF);   // [2][64][512] lo pairs

    const int g    = wid >> 1;          // gate 0=z,1=r,2=h (wid<6)
    const int kh   = wid & 1;           // K half
    const int kgrp = lane >> 4;         // 0..3
    const int arow = lane & 15;
    const int bcol = (wid < 6) ? (g*1024 + n*16 + (lane & 15)) : 0;

    // ---- one-time weight fragments in VGPRs (hi/lo bf16 split) ----
    bf16x8 Bh[16], Bl[16], XBh[4], XBl[4];
    if (wid < 6){
        #pragma unroll
        for (int kt = 0; kt < 16; ++kt){
            bf16x8 bh, bl;
            #pragma unroll
            for (int i = 0; i < 8; ++i){
                int k = kh*512 + kt*32 + kgrp*8 + i;
                float f = reck[k*G3 + bcol];
                __bf16 h = (__bf16)f;
                bh[i] = h;
                bl[i] = (__bf16)(f - (float)h);
            }
            Bh[kt] = bh; Bl[kt] = bl;
        }
        #pragma unroll
        for (int kt = 0; kt < 4; ++kt){
            bf16x8 bh, bl;
            #pragma unroll
            for (int i = 0; i < 8; ++i){
                int k = kh*128 + kt*32 + kgrp*8 + i;
                float f = kern[k*G3 + bcol];
                __bf16 h = (__bf16)f;
                bh[i] = h;
                bl[i] = (__bf16)(f - (float)h);
            }
            XBh[kt] = bh; XBl[kt] = bl;
        }
    }

    // combine-thread loop-invariant biases
    float cbz = 0.f, cbr = 0.f, cb0h = 0.f, cb1h = 0.f;
    if (tid < 256){
        int c = n*16 + (tid & 15);
        cbz  = bias[c]        + bias[G3 + c];
        cbr  = bias[1024 + c] + bias[G3 + 1024 + c];
        cb0h = bias[2048 + c];
        cb1h = bias[G3 + 2048 + c];
    }

    // ---- prologue: publish own 16x16 tile of h(0), gather x(0) ----
    float hloc = 0.f;
    if (tid < 256){
        int row = tid >> 4, jj = tid & 15;
        int grow = m*16 + row, gcol = n*16 + jj;
        float hv = hid[grow*Hh + gcol];
        hloc = hv;
        __bf16 hb = (__bf16)hv;
        __bf16 lb = (__bf16)(hv - (float)hb);
        unsigned int hu = (unsigned int)bfbits(hb);
        unsigned int lu = (unsigned int)bfbits(lb);
        unsigned int ph = __shfl_xor(hu, 1);
        unsigned int pl = __shfl_xor(lu, 1);
        int pidx = grow*512 + (gcol >> 1);   // parity 0 plane
        if ((jj & 1) == 0)
            __hip_atomic_store(&hHpl[pidx], (ph << 16) | hu, __ATOMIC_RELAXED, __HIP_MEMORY_SCOPE_AGENT);
        else
            __hip_atomic_store(&hLpl[pidx], (lu << 16) | pl, __ATOMIC_RELAXED, __HIP_MEMORY_SCOPE_AGENT);
    } else if (wid >= 6){
        gatherX(&sX[0][0][0], &sX[0][1][0], inp, emb, m, 0, tid - 384);
    }
    __syncthreads();   // drains vmcnt per wave -> h(0) stores ACKed at L3
    if (tid == 0)
        __hip_atomic_store(&flags[(m*64 + n)*4], 1u,
                           __ATOMIC_RELAXED, __HIP_MEMORY_SCOPE_AGENT);

    const int swz = (arow & 7) << 4;
    auto ldA = [&](const __bf16* base, int rowStrideB, int kbyte) -> bf16x8 {
        int off = (arow*rowStrideB + (kbyte ^ swz)) >> 1;
        return *(const bf16x8*)(base + off);
    };

    // ---- main sequential loop ----
    for (int t = 0; t < Tt; ++t){
        const int p = t & 1, qb = p ^ 1;

        // wait until all 64 blocks of this row-group published h(t):
        // 64-lane parallel flag poll, no RMW anywhere.
        if (wid == 0){
            int slot = (m*64 + lane)*4;
            int spin = 0;
            for (;;){
                unsigned int v = __hip_atomic_load(&flags[slot], __ATOMIC_RELAXED, __HIP_MEMORY_SCOPE_AGENT);
                if (__all(v >= (unsigned)(t + 1))) break;
                if (++spin > 50000000) break;   // safety valve: wrong, not wedged
                __builtin_amdgcn_s_sleep(1);
            }
        }
        __syncthreads();

        // stage h(t) slice (16 rows x 1024, hi+lo) into swizzled LDS.
        // sc1 relaxed atomic loads (L2-bypass, read from L3). All 16 loads
        // issued before any LDS write to keep full MLP.
        {
            const unsigned long long* sH =
                (const unsigned long long*)(hHpl + p*64*512 + (m*16)*512);
            const unsigned long long* sL =
                (const unsigned long long*)(hLpl + p*64*512 + (m*16)*512);
            unsigned long long vh[8], vl[8];
            #pragma unroll
            for (int i = 0; i < 8; ++i)
                vh[i] = __hip_atomic_load(&sH[i*512 + tid], __ATOMIC_RELAXED, __HIP_MEMORY_SCOPE_AGENT);
            #pragma unroll
            for (int i = 0; i < 8; ++i)
                vl[i] = __hip_atomic_load(&sL[i*512 + tid], __ATOMIC_RELAXED, __HIP_MEMORY_SCOPE_AGENT);
            #pragma unroll
            for (int i = 0; i < 8; ++i){
                int u = i*512 + tid;          // u64 index within [16][256]
                int row = u >> 8, c8 = u & 255;
                int off = row*2048 + ((c8*8) ^ ((row & 7) << 4));
                *(unsigned long long*)((char*)sHhi + off) = vh[i];
                *(unsigned long long*)((char*)sHlo + off) = vl[i];
            }
        }
        __syncthreads();

        if (wid < 6){
            f32x4 acc0  = {0,0,0,0}, acc1  = {0,0,0,0};
            f32x4 xacc0 = {0,0,0,0}, xacc1 = {0,0,0,0};
            // recurrent GEMM: K half = 512, 16 k-tiles, 3-term hi/lo split
            #pragma unroll
            for (int kt = 0; kt < 16; kt += 2){
                int kb0 = kh*1024 + kt*64 + kgrp*16;
                bf16x8 a0h = ldA(sHhi, 2048, kb0);
                bf16x8 a0l = ldA(sHlo, 2048, kb0);
                bf16x8 a1h = ldA(sHhi, 2048, kb0 + 64);
                bf16x8 a1l = ldA(sHlo, 2048, kb0 + 64);
                acc0 = mfma16(a0h, Bh[kt],   acc0);
                acc1 = mfma16(a1h, Bh[kt+1], acc1);
                acc0 = mfma16(a0h, Bl[kt],   acc0);
                acc1 = mfma16(a1h, Bl[kt+1], acc1);
                acc0 = mfma16(a0l, Bh[kt],   acc0);
                acc1 = mfma16(a1l, Bh[kt+1], acc1);
            }
            // input projection: K half = 128, 4 k-tiles
            const __bf16* xh_ = &sX[p][0][0];
            const __bf16* xl_ = &sX[p][1][0];
            if (g < 2){
                #pragma unroll
                for (int kt = 0; kt < 4; kt += 2){
                    int kb0 = kh*256 + kt*64 + kgrp*16;
                    bf16x8 a0h = ldA(xh_, 512, kb0);
                    bf16x8 a0l = ldA(xl_, 512, kb0);
                    bf16x8 a1h = ldA(xh_, 512, kb0 + 64);
                    bf16x8 a1l = ldA(xl_, 512, kb0 + 64);
                    acc0 = mfma16(a0h, XBh[kt],   acc0);
                    acc1 = mfma16(a1h, XBh[kt+1], acc1);
                    acc0 = mfma16(a0h, XBl[kt],   acc0);
                    acc1 = mfma16(a1h, XBl[kt+1], acc1);
                    acc0 = mfma16(a0l, XBh[kt],   acc0);
                    acc1 = mfma16(a1l, XBh[kt+1], acc1);
                }
            } else {
                #pragma unroll
                for (int kt = 0; kt < 4; kt += 2){
                    int kb0 = kh*256 + kt*64 + kgrp*16;
                    bf16x8 a0h = ldA(xh_, 512, kb0);
                    bf16x8 a0l = ldA(xl_, 512, kb0);
                    bf16x8 a1h = ldA(xh_, 512, kb0 + 64);
                    bf16x8 a1l = ldA(xl_, 512, kb0 + 64);
                    xacc0 = mfma16(a0h, XBh[kt],   xacc0);
                    xacc1 = mfma16(a1h, XBh[kt+1], xacc1);
                    xacc0 = mfma16(a0h, XBl[kt],   xacc0);
                    xacc1 = mfma16(a1h, XBl[kt+1], xacc1);
                    xacc0 = mfma16(a0l, XBh[kt],   xacc0);
                    xacc1 = mfma16(a1l, XBh[kt+1], xacc1);
                }
            }
            f32x4 rsum = acc0 + acc1;
            int tb = (g < 2) ? (g*2 + kh) : (4 + kh);
            #pragma unroll
            for (int r = 0; r < 4; ++r)
                sTile[tb][kgrp*68 + r*16 + (lane & 15)] = rsum[r];
            if (g == 2){
                f32x4 xs = xacc0 + xacc1;
                #pragma unroll
                for (int r = 0; r < 4; ++r)
                    sTile[6 + kh][kgrp*68 + r*16 + (lane & 15)] = xs[r];
            }
        } else {
            if (t + 1 < Tt)
                gatherX(&sX[qb][0][0], &sX[qb][1][0], inp, emb, m, t + 1, tid - 384);
        }
        __syncthreads();

        // gate nonlinearity + state update (exact f32 state kept in-register)
        if (tid < 256){
            int row = tid >> 4, jj = tid & 15;
            int ix = (row >> 2)*68 + (row & 3)*16 + jj;
            float pz = sTile[0][ix] + sTile[1][ix] + cbz;
            float pr = sTile[2][ix] + sTile[3][ix] + cbr;
            float rh = sTile[4][ix] + sTile[5][ix] + cb1h;
            float xh = sTile[6][ix] + sTile[7][ix] + cb0h;
            float z  = 1.f/(1.f + expf(-pz));
            float r  = 1.f/(1.f + expf(-pr));
            float hhat = tanhf(xh + r*rh);
            int grow = m*16 + row, gcol = n*16 + jj;
            float hn = z*hloc + (1.f - z)*hhat;
            out[((long)grow*Tt + t)*Hh + gcol] = hn;
            hloc = hn;
            __bf16 nh = (__bf16)hn;
            __bf16 nl = (__bf16)(hn - (float)nh);
            unsigned int hu = (unsigned int)bfbits(nh);
            unsigned int lu = (unsigned int)bfbits(nl);
            unsigned int ph = __shfl_xor(hu, 1);
            unsigned int pl = __shfl_xor(lu, 1);
            int pidx = qb*64*512 + grow*512 + (gcol >> 1);
            if ((jj & 1) == 0)
                __hip_atomic_store(&hHpl[pidx], (ph << 16) | hu, __ATOMIC_RELAXED, __HIP_MEMORY_SCOPE_AGENT);
            else
                __hip_atomic_store(&hLpl[pidx], (lu << 16) | pl, __ATOMIC_RELAXED, __HIP_MEMORY_SCOPE_AGENT);
            if (t == Tt - 1)
                out[(long)Bb*Tt*Hh + grow*Hh + gcol] = hn;  // final state
        }
        __syncthreads();   // drains all waves' vmcnt -> h' ACKed at L3
        if (tid == 0)
            __hip_atomic_store(&flags[(m*64 + n)*4], (unsigned)(t + 2),
                               __ATOMIC_RELAXED, __HIP_MEMORY_SCOPE_AGENT);
    }
}

extern "C" void kernel_launch(void* const* d_in, const int* in_sizes, int n_in,
                              void* d_out, int out_size, void* d_ws, size_t ws_size,
                              hipStream_t stream)
{
    (void)in_sizes; (void)n_in; (void)out_size; (void)ws_size;
    const int*   inp  = (const int*)  d_in[0];
    const float* hid  = (const float*)d_in[1];
    const float* emb  = (const float*)d_in[2];
    const float* kern = (const float*)d_in[3];
    const float* reck = (const float*)d_in[4];
    const float* bias = (const float*)d_in[5];
    float* out = (float*)d_out;
    unsigned char* ws = (unsigned char*)d_ws;

    // zero the per-block flags (poisoned / left over from previous replay)
    hipMemsetAsync(ws, 0, FLAG_BYTES, stream);

    void* args[] = {(void*)&inp, (void*)&hid, (void*)&emb, (void*)&kern,
                    (void*)&reck, (void*)&bias, (void*)&out, (void*)&ws};
    hipLaunchCooperativeKernel((void*)gru_persist, dim3(256), dim3(512),
                               args, 0, stream);
}

// Round 5
// 2392.420 us; speedup vs baseline: 1.4600x; 1.4600x over previous
//
#include <hip/hip_runtime.h>

#define Bb 64
#define Tt 512
#define Dd 256
#define Hh 1024
#define G3 3072

// workspace layout
#define FLAG_BYTES 4096                        // 256 slots x 16 B
#define HH_OFF     FLAG_BYTES                  // [2][64][512] u32 (bf16-hi pairs) = 256 KB
#define HL_OFF     (FLAG_BYTES + 262144)       // [2][64][512] u32 (bf16-lo pairs)

typedef __attribute__((ext_vector_type(8))) __bf16 bf16x8;
typedef __attribute__((ext_vector_type(4))) float f32x4;

static __device__ __forceinline__ f32x4 mfma16(bf16x8 a, bf16x8 b, f32x4 c){
    return __builtin_amdgcn_mfma_f32_16x16x32_bf16(a, b, c, 0, 0, 0);
}
static __device__ __forceinline__ unsigned short bfbits(__bf16 v){
    return __builtin_bit_cast(unsigned short, v);
}

// gather embedding rows for timestep t into LDS x-buffer (hi/lo bf16 split),
// swizzled to match the MFMA A-fragment ds_read pattern. 128 threads (lt 0..127).
// (round-2 verbatim — verified passing)
__device__ __forceinline__ void gatherX(__bf16* sxh, __bf16* sxl,
                                        const int* inp, const float* emb,
                                        int m, int t, int lt)
{
    int row = lt >> 3, c8 = lt & 7;
    int grow = m*16 + row;
    int tok = inp[grow*Tt + t];
    const float* er = emb + (long)tok * Dd;
    int swz = (row & 7) << 4;
    #pragma unroll
    for (int qq = 0; qq < 8; ++qq){
        int c = c8 + qq*8;                       // 4-float chunk, 0..63
        float4 v = *(const float4*)(er + c*4);
        int boff = row*512 + ((c*8) ^ swz);      // byte offset, 8B-aligned
        float vv[4] = {v.x, v.y, v.z, v.w};
        unsigned long long Hp = 0, Lp = 0;
        #pragma unroll
        for (int e = 0; e < 4; ++e){
            __bf16 hb = (__bf16)vv[e];
            __bf16 lb = (__bf16)(vv[e] - (float)hb);
            Hp |= (unsigned long long)bfbits(hb) << (16*e);
            Lp |= (unsigned long long)bfbits(lb) << (16*e);
        }
        *(unsigned long long*)((char*)sxh + boff) = Hp;
        *(unsigned long long*)((char*)sxl + boff) = Lp;
    }
}

extern "C" __global__ void __launch_bounds__(512, 2)
gru_persist(const int* __restrict__ inp, const float* __restrict__ hid,
            const float* __restrict__ emb, const float* __restrict__ kern,
            const float* __restrict__ reck, const float* __restrict__ bias,
            float* __restrict__ out, unsigned char* __restrict__ ws)
{
    __shared__ __bf16 sHhi[16*1024];     // 32 KB, swizzled (r2 layout)
    __shared__ __bf16 sHlo[16*1024];     // 32 KB
    __shared__ __bf16 sX[2][2][16*256];  // [buf][hi/lo], 32 KB total (r2 layout)
    __shared__ float  sTile[8][4][256];  // [kwave][z,r,hrec,hx][row*16+col], 32 KB

    const int tid  = threadIdx.x;
    const int wid  = tid >> 6;
    const int lane = tid & 63;
    const int blk  = blockIdx.x;
    const int m = blk & 3;       // row group: rows 16m..16m+15
    const int n = blk >> 2;      // j group:  j = 16n..16n+15

    unsigned int* flags = (unsigned int*)ws;             // slot (m*64+n)*4, 16B stride
    unsigned int* hHpl = (unsigned int*)(ws + HH_OFF);   // [2][64][512] hi pairs
    unsigned int* hLpl = (unsigned int*)(ws + HL_OFF);   // [2][64][512] lo pairs

    const int e    = wid;               // K-eighth owned by this wave (0..7)
    const int kgrp = lane >> 4;         // 0..3 (k sub-block)
    const int arow = lane & 15;         // A row / B col within tile

    // ---- one-time weight fragments in VGPRs (hi/lo bf16 split) ----
    // wave e owns rec-K rows [128e, 128e+128) and input-K rows [32e, 32e+32),
    // for ALL 3 gates.
    bf16x8 Bh[3][4], Bl[3][4], XBh[3], XBl[3];
    #pragma unroll
    for (int g = 0; g < 3; ++g){
        #pragma unroll
        for (int ks = 0; ks < 4; ++ks){
            bf16x8 bh, bl;
            #pragma unroll
            for (int i = 0; i < 8; ++i){
                int k = e*128 + ks*32 + kgrp*8 + i;
                float f = reck[k*G3 + g*1024 + n*16 + arow];
                __bf16 h = (__bf16)f;
                bh[i] = h;
                bl[i] = (__bf16)(f - (float)h);
            }
            Bh[g][ks] = bh; Bl[g][ks] = bl;
        }
        {
            bf16x8 bh, bl;
            #pragma unroll
            for (int i = 0; i < 8; ++i){
                int k = e*32 + kgrp*8 + i;
                float f = kern[k*G3 + g*1024 + n*16 + arow];
                __bf16 h = (__bf16)f;
                bh[i] = h;
                bl[i] = (__bf16)(f - (float)h);
            }
            XBh[g] = bh; XBl[g] = bl;
        }
    }

    // combine-thread loop-invariant biases (r2 verbatim)
    float cbz = 0.f, cbr = 0.f, cb0h = 0.f, cb1h = 0.f;
    if (tid < 256){
        int c = n*16 + (tid & 15);
        cbz  = bias[c]        + bias[G3 + c];
        cbr  = bias[1024 + c] + bias[G3 + 1024 + c];
        cb0h = bias[2048 + c];
        cb1h = bias[G3 + 2048 + c];
    }

    // ---- prologue: publish own 16x16 tile of h(0), gather x(0) (r2 verbatim) ----
    float hloc = 0.f;
    if (tid < 256){
        int row = tid >> 4, jj = tid & 15;
        int grow = m*16 + row, gcol = n*16 + jj;
        float hv = hid[grow*Hh + gcol];
        hloc = hv;
        __bf16 hb = (__bf16)hv;
        __bf16 lb = (__bf16)(hv - (float)hb);
        unsigned int hu = (unsigned int)bfbits(hb);
        unsigned int lu = (unsigned int)bfbits(lb);
        unsigned int ph = __shfl_xor(hu, 1);
        unsigned int pl = __shfl_xor(lu, 1);
        int pidx = grow*512 + (gcol >> 1);   // parity 0 plane
        if ((jj & 1) == 0)
            __hip_atomic_store(&hHpl[pidx], (ph << 16) | hu, __ATOMIC_RELAXED, __HIP_MEMORY_SCOPE_AGENT);
        else
            __hip_atomic_store(&hLpl[pidx], (lu << 16) | pl, __ATOMIC_RELAXED, __HIP_MEMORY_SCOPE_AGENT);
    } else if (wid >= 6){
        gatherX(&sX[0][0][0], &sX[0][1][0], inp, emb, m, 0, tid - 384);
    }
    __syncthreads();   // drains vmcnt per wave -> h(0) stores ACKed at L3
    if (tid == 0)
        __hip_atomic_store(&flags[(m*64 + n)*4], 1u,
                           __ATOMIC_RELAXED, __HIP_MEMORY_SCOPE_AGENT);

    const int swz = (arow & 7) << 4;
    auto ldA = [&](const __bf16* base, int rowStrideB, int kbyte) -> bf16x8 {
        int off = (arow*rowStrideB + (kbyte ^ swz)) >> 1;
        return *(const bf16x8*)(base + off);
    };

    // ---- main sequential loop ----
    for (int t = 0; t < Tt; ++t){
        const int p = t & 1, qb = p ^ 1;

        // wave 0: 64-lane parallel flag poll (r2 verbatim)
        if (wid == 0){
            int slot = (m*64 + lane)*4;
            int spin = 0;
            for (;;){
                unsigned int v = __hip_atomic_load(&flags[slot], __ATOMIC_RELAXED, __HIP_MEMORY_SCOPE_AGENT);
                if (__all(v >= (unsigned)(t + 1))) break;
                if (++spin > 50000000) break;   // safety valve: wrong, not wedged
                __builtin_amdgcn_s_sleep(1);
            }
        }
        __syncthreads();

        // stage h(t) slice into swizzled LDS (r2 verbatim)
        {
            const unsigned long long* sH =
                (const unsigned long long*)(hHpl + p*64*512 + (m*16)*512);
            const unsigned long long* sL =
                (const unsigned long long*)(hLpl + p*64*512 + (m*16)*512);
            unsigned long long vh[8], vl[8];
            #pragma unroll
            for (int i = 0; i < 8; ++i)
                vh[i] = __hip_atomic_load(&sH[i*512 + tid], __ATOMIC_RELAXED, __HIP_MEMORY_SCOPE_AGENT);
            #pragma unroll
            for (int i = 0; i < 8; ++i)
                vl[i] = __hip_atomic_load(&sL[i*512 + tid], __ATOMIC_RELAXED, __HIP_MEMORY_SCOPE_AGENT);
            #pragma unroll
            for (int i = 0; i < 8; ++i){
                int u = i*512 + tid;          // u64 index within [16][256]
                int row = u >> 8, c8 = u & 255;
                int off = row*2048 + ((c8*8) ^ ((row & 7) << 4));
                *(unsigned long long*)((char*)sHhi + off) = vh[i];
                *(unsigned long long*)((char*)sHlo + off) = vl[i];
            }
        }
        __syncthreads();

        // GEMM: every wave computes its K-eighth for ALL 3 gates (3-term hi/lo).
        {
            f32x4 acc0 = {0,0,0,0}, acc1 = {0,0,0,0};
            f32x4 acc2 = {0,0,0,0}, acc3 = {0,0,0,0};
            #pragma unroll
            for (int ks = 0; ks < 4; ++ks){
                int kb0 = e*256 + ks*64 + kgrp*16;      // byte offset in 2048B row
                bf16x8 Ah = ldA(sHhi, 2048, kb0);
                bf16x8 Al = ldA(sHlo, 2048, kb0);
                acc0 = mfma16(Ah, Bh[0][ks], acc0);
                acc1 = mfma16(Ah, Bh[1][ks], acc1);
                acc2 = mfma16(Ah, Bh[2][ks], acc2);
                acc0 = mfma16(Ah, Bl[0][ks], acc0);
                acc1 = mfma16(Ah, Bl[1][ks], acc1);
                acc2 = mfma16(Ah, Bl[2][ks], acc2);
                acc0 = mfma16(Al, Bh[0][ks], acc0);
                acc1 = mfma16(Al, Bh[1][ks], acc1);
                acc2 = mfma16(Al, Bh[2][ks], acc2);
            }
            {
                int kbx = e*64 + kgrp*16;               // byte offset in 512B row
                bf16x8 Ah = ldA(&sX[p][0][0], 512, kbx);
                bf16x8 Al = ldA(&sX[p][1][0], 512, kbx);
                acc0 = mfma16(Ah, XBh[0], acc0);
                acc1 = mfma16(Ah, XBh[1], acc1);
                acc3 = mfma16(Ah, XBh[2], acc3);
                acc0 = mfma16(Ah, XBl[0], acc0);
                acc1 = mfma16(Ah, XBl[1], acc1);
                acc3 = mfma16(Ah, XBl[2], acc3);
                acc0 = mfma16(Al, XBh[0], acc0);
                acc1 = mfma16(Al, XBh[1], acc1);
                acc3 = mfma16(Al, XBh[2], acc3);
            }
            #pragma unroll
            for (int r = 0; r < 4; ++r){
                int ix = (kgrp*4 + r)*16 + arow;        // C/D: row=(lane>>4)*4+r, col=lane&15
                sTile[e][0][ix] = acc0[r];
                sTile[e][1][ix] = acc1[r];
                sTile[e][2][ix] = acc2[r];
                sTile[e][3][ix] = acc3[r];
            }
        }
        __syncthreads();

        // gate nonlinearity + state update (r2 verbatim, 8-way partial sum)
        if (tid < 256){
            int row = tid >> 4, jj = tid & 15;
            int ix = row*16 + jj;
            float pz = cbz, pr = cbr, rh = cb1h, xh = cb0h;
            #pragma unroll
            for (int w = 0; w < 8; ++w){
                pz += sTile[w][0][ix];
                pr += sTile[w][1][ix];
                rh += sTile[w][2][ix];
                xh += sTile[w][3][ix];
            }
            float z  = 1.f/(1.f + expf(-pz));
            float r  = 1.f/(1.f + expf(-pr));
            float hhat = tanhf(xh + r*rh);
            int grow = m*16 + row, gcol = n*16 + jj;
            float hn = z*hloc + (1.f - z)*hhat;
            out[((long)grow*Tt + t)*Hh + gcol] = hn;
            hloc = hn;
            __bf16 nh = (__bf16)hn;
            __bf16 nl = (__bf16)(hn - (float)nh);
            unsigned int hu = (unsigned int)bfbits(nh);
            unsigned int lu = (unsigned int)bfbits(nl);
            unsigned int ph = __shfl_xor(hu, 1);
            unsigned int pl = __shfl_xor(lu, 1);
            int pidx = qb*32768 + grow*512 + (gcol >> 1);
            if ((jj & 1) == 0)
                __hip_atomic_store(&hHpl[pidx], (ph << 16) | hu, __ATOMIC_RELAXED, __HIP_MEMORY_SCOPE_AGENT);
            else
                __hip_atomic_store(&hLpl[pidx], (lu << 16) | pl, __ATOMIC_RELAXED, __HIP_MEMORY_SCOPE_AGENT);
            if (t == Tt - 1)
                out[(long)Bb*Tt*Hh + grow*Hh + gcol] = hn;  // final state
        } else if (wid >= 6){
            // gather x(t+1) concurrently with the combine waves
            if (t + 1 < Tt)
                gatherX(&sX[qb][0][0], &sX[qb][1][0], inp, emb, m, t + 1, tid - 384);
        }
        __syncthreads();   // drains all waves' vmcnt -> h' ACKed at L3
        if (tid == 0)
            __hip_atomic_store(&flags[(m*64 + n)*4], (unsigned)(t + 2),
                               __ATOMIC_RELAXED, __HIP_MEMORY_SCOPE_AGENT);
    }
}

extern "C" void kernel_launch(void* const* d_in, const int* in_sizes, int n_in,
                              void* d_out, int out_size, void* d_ws, size_t ws_size,
                              hipStream_t stream)
{
    (void)in_sizes; (void)n_in; (void)out_size; (void)ws_size;
    const int*   inp  = (const int*)  d_in[0];
    const float* hid  = (const float*)d_in[1];
    const float* emb  = (const float*)d_in[2];
    const float* kern = (const float*)d_in[3];
    const float* reck = (const float*)d_in[4];
    const float* bias = (const float*)d_in[5];
    float* out = (float*)d_out;
    unsigned char* ws = (unsigned char*)d_ws;

    // zero the per-block flags (poisoned / left over from previous replay)
    hipMemsetAsync(ws, 0, FLAG_BYTES, stream);

    void* args[] = {(void*)&inp, (void*)&hid, (void*)&emb, (void*)&kern,
                    (void*)&reck, (void*)&bias, (void*)&out, (void*)&ws};
    hipLaunchCooperativeKernel((void*)gru_persist, dim3(256), dim3(512),
                               args, 0, stream);
}